// Round 1
// baseline (1544.626 us; speedup 1.0000x reference)
//
#include <hip/hip_runtime.h>
#include <hip/hip_bf16.h>
#include <stdint.h>

#define NUM_CAMS 12
#define NUM_JOINTS 23
#define JP 32                 // joints padded to 32 bf16 = 64B per voxel-block
#define G 104
#define HALF 52
#define L 160
#define HM_W 512
#define HM_H 512
#define HW (HM_W * HM_H)      // 262144
#define G3 (G * G * G)        // 1124864 (divisible by 256 -> 4394 blocks)
#define OFFSET (-160.0f)
#define SPACING 2.0f

__device__ __forceinline__ uint32_t f32_to_bf16_rne(float f) {
    uint32_t b = __float_as_uint(f);
    return (b + 0x7fffu + ((b >> 16) & 1u)) >> 16;
}

// Kernel 1: heatmaps [B*C, J, HW] f32  ->  trans [B*C, HW, JP] bf16
// thread = one (bc, hw); reads 23 coalesced scalars, writes one full 64B line.
__global__ __launch_bounds__(256) void transpose_kernel(
    const float* __restrict__ heat, uint16_t* __restrict__ trans)
{
    const int hw = blockIdx.x * 256 + threadIdx.x;
    const int bc = blockIdx.y;
    const float* src = heat + (size_t)bc * NUM_JOINTS * HW + hw;

    uint32_t packed[JP / 2];
#pragma unroll
    for (int i = 0; i < JP / 2; i++) packed[i] = 0u;

#pragma unroll
    for (int j = 0; j < NUM_JOINTS; j++) {
        uint32_t r = f32_to_bf16_rne(src[(size_t)j * HW]);
        if (j & 1) packed[j >> 1] |= (r << 16);
        else       packed[j >> 1] |= r;
    }

    uint4* dst = (uint4*)(trans + ((size_t)bc * HW + hw) * JP);
    dst[0] = make_uint4(packed[0],  packed[1],  packed[2],  packed[3]);
    dst[1] = make_uint4(packed[4],  packed[5],  packed[6],  packed[7]);
    dst[2] = make_uint4(packed[8],  packed[9],  packed[10], packed[11]);
    dst[3] = make_uint4(packed[12], packed[13], packed[14], packed[15]);
}

// Kernel 2: per (b, voxel): loop 12 cams, read lookup int2 (coalesced along z),
// gather one 64B-aligned line of 23 bf16 joints, accumulate fp32, write mean.
__global__ __launch_bounds__(256) void gather_kernel(
    const uint16_t* __restrict__ trans, const float* __restrict__ center,
    const int* __restrict__ lookup, float* __restrict__ out)
{
    const int vox = blockIdx.x * 256 + threadIdx.x;   // < G3, z fastest
    const int b = blockIdx.y;

    const int z = vox % G;
    const int t = vox / G;
    const int y = t % G;
    const int x = t / G;

    int s0 = (int)((center[b * 3 + 0] - OFFSET) / SPACING) - HALF;
    int s1 = (int)((center[b * 3 + 1] - OFFSET) / SPACING) - HALF;
    int s2 = (int)((center[b * 3 + 2] - OFFSET) / SPACING) - HALF;
    // dynamic_slice clamp semantics
    s0 = min(max(s0, 0), L - G);
    s1 = min(max(s1, 0), L - G);
    s2 = min(max(s2, 0), L - G);

    const int xi = s0 + x, yi = s1 + y, zi = s2 + z;

    float acc[NUM_JOINTS];
#pragma unroll
    for (int j = 0; j < NUM_JOINTS; j++) acc[j] = 0.0f;

#pragma unroll
    for (int c = 0; c < NUM_CAMS; c++) {
        const size_t lidx = ((((size_t)c * L + xi) * L + yi) * L + zi) * 2;
        const int2 uv = *(const int2*)(lookup + lidx);     // (u, v), 8B aligned
        const int flat = uv.y * HM_W + uv.x;

        const uint4* p = (const uint4*)(
            trans + (((size_t)b * NUM_CAMS + c) * HW + (size_t)flat) * JP);
        const uint4 q0 = p[0];
        const uint4 q1 = p[1];
        const uint4 q2 = p[2];   // 24 bf16; element 23 is pad

        uint32_t w[12] = {q0.x, q0.y, q0.z, q0.w,
                          q1.x, q1.y, q1.z, q1.w,
                          q2.x, q2.y, q2.z, q2.w};
#pragma unroll
        for (int k = 0; k < 11; k++) {
            acc[2 * k]     += __uint_as_float(w[k] << 16);
            acc[2 * k + 1] += __uint_as_float(w[k] & 0xffff0000u);
        }
        acc[22] += __uint_as_float(w[11] << 16);
    }

    const float scale = 1.0f / (float)NUM_CAMS;
    float* o = out + (size_t)b * NUM_JOINTS * G3 + vox;
#pragma unroll
    for (int j = 0; j < NUM_JOINTS; j++)
        o[(size_t)j * G3] = acc[j] * scale;
}

// Fallback (ws too small): direct fp32 gather, 23 strided lines per cam-voxel.
__global__ __launch_bounds__(256) void gather_direct_kernel(
    const float* __restrict__ heat, const float* __restrict__ center,
    const int* __restrict__ lookup, float* __restrict__ out)
{
    const int vox = blockIdx.x * 256 + threadIdx.x;
    const int b = blockIdx.y;

    const int z = vox % G;
    const int t = vox / G;
    const int y = t % G;
    const int x = t / G;

    int s0 = (int)((center[b * 3 + 0] - OFFSET) / SPACING) - HALF;
    int s1 = (int)((center[b * 3 + 1] - OFFSET) / SPACING) - HALF;
    int s2 = (int)((center[b * 3 + 2] - OFFSET) / SPACING) - HALF;
    s0 = min(max(s0, 0), L - G);
    s1 = min(max(s1, 0), L - G);
    s2 = min(max(s2, 0), L - G);

    const int xi = s0 + x, yi = s1 + y, zi = s2 + z;

    float acc[NUM_JOINTS];
#pragma unroll
    for (int j = 0; j < NUM_JOINTS; j++) acc[j] = 0.0f;

    for (int c = 0; c < NUM_CAMS; c++) {
        const size_t lidx = ((((size_t)c * L + xi) * L + yi) * L + zi) * 2;
        const int2 uv = *(const int2*)(lookup + lidx);
        const int flat = uv.y * HM_W + uv.x;
        const float* hp = heat + (((size_t)b * NUM_CAMS + c) * NUM_JOINTS) * HW
                               + (size_t)flat;
#pragma unroll
        for (int j = 0; j < NUM_JOINTS; j++)
            acc[j] += hp[(size_t)j * HW];
    }

    const float scale = 1.0f / (float)NUM_CAMS;
    float* o = out + (size_t)b * NUM_JOINTS * G3 + vox;
#pragma unroll
    for (int j = 0; j < NUM_JOINTS; j++)
        o[(size_t)j * G3] = acc[j] * scale;
}

extern "C" void kernel_launch(void* const* d_in, const int* in_sizes, int n_in,
                              void* d_out, int out_size, void* d_ws, size_t ws_size,
                              hipStream_t stream)
{
    const float* heat   = (const float*)d_in[0];
    const float* center = (const float*)d_in[1];
    const int*   lookup = (const int*)d_in[2];
    float* out = (float*)d_out;

    const int B = in_sizes[1] / 3;   // = 2
    const size_t need = (size_t)B * NUM_CAMS * HW * JP * sizeof(uint16_t); // ~403 MB

    if (ws_size >= need) {
        uint16_t* trans = (uint16_t*)d_ws;
        dim3 g1(HW / 256, B * NUM_CAMS);          // 1024 x 24
        transpose_kernel<<<g1, 256, 0, stream>>>(heat, trans);
        dim3 g2(G3 / 256, B);                      // 4394 x 2
        gather_kernel<<<g2, 256, 0, stream>>>(trans, center, lookup, out);
    } else {
        dim3 g2(G3 / 256, B);
        gather_direct_kernel<<<g2, 256, 0, stream>>>(heat, center, lookup, out);
    }
}

// Round 2
// 1449.470 us; speedup vs baseline: 1.0656x; 1.0656x over previous
//
#include <hip/hip_runtime.h>
#include <stdint.h>

#define NUM_CAMS 12
#define NUM_JOINTS 23
#define RB 32                 // record bytes: 23 u8 joints + pad, 32B aligned
#define RW 8                  // record dwords
#define G 104
#define HALF 52
#define L 160
#define HM_W 512
#define HM_H 512
#define HW (HM_W * HM_H)      // 262144
#define G3 (G * G * G)        // 1124864
#define OFFSET (-160.0f)
#define SPACING 2.0f

// Kernel 1: heatmaps [B*C, J, HW] f32 -> trans [B*C, HW, RB] u8
// Thread handles 4 consecutive hw: 23 coalesced float4 reads (1KB/wave/instr),
// 128B contiguous store per thread (8KB/wave, fully coalesced).
__global__ __launch_bounds__(256) void quant_transpose_kernel(
    const float* __restrict__ heat, uint32_t* __restrict__ trans)
{
    const int hw4 = (blockIdx.x * 256 + threadIdx.x) * 4;
    const int bc = blockIdx.y;
    const float* src = heat + (size_t)bc * NUM_JOINTS * HW + hw4;

    uint32_t pk[4][RW];
#pragma unroll
    for (int r = 0; r < 4; r++)
#pragma unroll
        for (int k = 0; k < RW; k++) pk[r][k] = 0u;

#pragma unroll
    for (int j = 0; j < NUM_JOINTS; j++) {
        const float4 v = *(const float4*)(src + (size_t)j * HW);
        const int k = j >> 2, sh = (j & 3) * 8;
        uint32_t q0 = (uint32_t)fmaf(v.x, 255.0f, 0.5f);
        uint32_t q1 = (uint32_t)fmaf(v.y, 255.0f, 0.5f);
        uint32_t q2 = (uint32_t)fmaf(v.z, 255.0f, 0.5f);
        uint32_t q3 = (uint32_t)fmaf(v.w, 255.0f, 0.5f);
        pk[0][k] |= q0 << sh;
        pk[1][k] |= q1 << sh;
        pk[2][k] |= q2 << sh;
        pk[3][k] |= q3 << sh;
    }

    uint4* dst = (uint4*)(trans + ((size_t)bc * HW + hw4) * RW);
#pragma unroll
    for (int r = 0; r < 4; r++) {
        dst[2 * r]     = make_uint4(pk[r][0], pk[r][1], pk[r][2], pk[r][3]);
        dst[2 * r + 1] = make_uint4(pk[r][4], pk[r][5], pk[r][6], pk[r][7]);
    }
}

// Kernel 2: per (b, voxel): 12 lookup int2 loads + 12 record loads (24B each)
// ALL issued before accumulation (max MLP). SWAR u8->u16x2 accumulation.
__global__ __launch_bounds__(256, 4) void gather_kernel(
    const uint8_t* __restrict__ trans, const float* __restrict__ center,
    const int* __restrict__ lookup, float* __restrict__ out)
{
    const int vox = blockIdx.x * 256 + threadIdx.x;   // z fastest
    const int b = blockIdx.y;

    const int z = vox % G;
    const int t = vox / G;
    const int y = t % G;
    const int x = t / G;

    int s0 = (int)((center[b * 3 + 0] - OFFSET) / SPACING) - HALF;
    int s1 = (int)((center[b * 3 + 1] - OFFSET) / SPACING) - HALF;
    int s2 = (int)((center[b * 3 + 2] - OFFSET) / SPACING) - HALF;
    s0 = min(max(s0, 0), L - G);
    s1 = min(max(s1, 0), L - G);
    s2 = min(max(s2, 0), L - G);

    const int xi = s0 + x, yi = s1 + y, zi = s2 + z;
    const size_t lbase = (((size_t)xi * L + yi) * L + zi) * 2;

    // phase 1: all lookup loads in flight
    int2 uv[NUM_CAMS];
#pragma unroll
    for (int c = 0; c < NUM_CAMS; c++)
        uv[c] = *(const int2*)(lookup + (size_t)c * (L * L * L * 2) + lbase);

    // phase 2: all record loads in flight (24B = dwordx4 + dwordx2 each)
    const uint8_t* tb = trans + (size_t)b * NUM_CAMS * HW * RB;
    uint4 qa[NUM_CAMS];
    uint2 qb[NUM_CAMS];
#pragma unroll
    for (int c = 0; c < NUM_CAMS; c++) {
        const int flat = uv[c].y * HM_W + uv[c].x;
        const uint8_t* p = tb + ((size_t)c * HW + (size_t)flat) * RB;
        qa[c] = *(const uint4*)p;
        qb[c] = *(const uint2*)(p + 16);
    }

    // phase 3: SWAR accumulate — two u8 values per u16 lane, 12*255 < 65536
    uint32_t accLo[6] = {0, 0, 0, 0, 0, 0};
    uint32_t accHi[6] = {0, 0, 0, 0, 0, 0};
#pragma unroll
    for (int c = 0; c < NUM_CAMS; c++) {
        const uint32_t d[6] = {qa[c].x, qa[c].y, qa[c].z, qa[c].w,
                               qb[c].x, qb[c].y};
#pragma unroll
        for (int k = 0; k < 6; k++) {
            accLo[k] += d[k] & 0x00ff00ffu;          // joints 4k, 4k+2
            accHi[k] += (d[k] >> 8) & 0x00ff00ffu;   // joints 4k+1, 4k+3
        }
    }

    const float scale = 1.0f / (255.0f * (float)NUM_CAMS);
    float* o = out + (size_t)b * NUM_JOINTS * G3 + vox;
#pragma unroll
    for (int k = 0; k < 6; k++) {
        const int j = 4 * k;
        o[(size_t)j * G3]       = (float)(accLo[k] & 0xffffu) * scale;
        o[(size_t)(j + 1) * G3] = (float)(accHi[k] & 0xffffu) * scale;
        o[(size_t)(j + 2) * G3] = (float)(accLo[k] >> 16) * scale;
        if (j + 3 < NUM_JOINTS)
            o[(size_t)(j + 3) * G3] = (float)(accHi[k] >> 16) * scale;
    }
}

// Fallback (ws too small): direct fp32 gather from native layout.
__global__ __launch_bounds__(256) void gather_direct_kernel(
    const float* __restrict__ heat, const float* __restrict__ center,
    const int* __restrict__ lookup, float* __restrict__ out)
{
    const int vox = blockIdx.x * 256 + threadIdx.x;
    const int b = blockIdx.y;

    const int z = vox % G;
    const int t = vox / G;
    const int y = t % G;
    const int x = t / G;

    int s0 = (int)((center[b * 3 + 0] - OFFSET) / SPACING) - HALF;
    int s1 = (int)((center[b * 3 + 1] - OFFSET) / SPACING) - HALF;
    int s2 = (int)((center[b * 3 + 2] - OFFSET) / SPACING) - HALF;
    s0 = min(max(s0, 0), L - G);
    s1 = min(max(s1, 0), L - G);
    s2 = min(max(s2, 0), L - G);

    const int xi = s0 + x, yi = s1 + y, zi = s2 + z;

    float acc[NUM_JOINTS];
#pragma unroll
    for (int j = 0; j < NUM_JOINTS; j++) acc[j] = 0.0f;

    for (int c = 0; c < NUM_CAMS; c++) {
        const size_t lidx = ((((size_t)c * L + xi) * L + yi) * L + zi) * 2;
        const int2 uvc = *(const int2*)(lookup + lidx);
        const int flat = uvc.y * HM_W + uvc.x;
        const float* hp = heat + (((size_t)b * NUM_CAMS + c) * NUM_JOINTS) * HW
                               + (size_t)flat;
#pragma unroll
        for (int j = 0; j < NUM_JOINTS; j++)
            acc[j] += hp[(size_t)j * HW];
    }

    const float scale = 1.0f / (float)NUM_CAMS;
    float* o = out + (size_t)b * NUM_JOINTS * G3 + vox;
#pragma unroll
    for (int j = 0; j < NUM_JOINTS; j++)
        o[(size_t)j * G3] = acc[j] * scale;
}

extern "C" void kernel_launch(void* const* d_in, const int* in_sizes, int n_in,
                              void* d_out, int out_size, void* d_ws, size_t ws_size,
                              hipStream_t stream)
{
    const float* heat   = (const float*)d_in[0];
    const float* center = (const float*)d_in[1];
    const int*   lookup = (const int*)d_in[2];
    float* out = (float*)d_out;

    const int B = in_sizes[1] / 3;   // = 2
    const size_t need = (size_t)B * NUM_CAMS * HW * RB;   // ~201 MB

    if (ws_size >= need) {
        uint32_t* trans = (uint32_t*)d_ws;
        dim3 g1(HW / (256 * 4), B * NUM_CAMS);     // 256 x 24
        quant_transpose_kernel<<<g1, 256, 0, stream>>>(heat, trans);
        dim3 g2(G3 / 256, B);                       // 4394 x 2
        gather_kernel<<<g2, 256, 0, stream>>>((const uint8_t*)trans, center,
                                              lookup, out);
    } else {
        dim3 g2(G3 / 256, B);
        gather_direct_kernel<<<g2, 256, 0, stream>>>(heat, center, lookup, out);
    }
}